// Round 8
// baseline (172.038 us; speedup 1.0000x reference)
//
#include <hip/hip_runtime.h>
#include <math.h>

// ws layout (floats)
#define WS_WEFF 0        // 45 cfgs * 225 taps = 10125
#define WS_M    10240    // 4 * 961 = 3844
#define WS_OFF  14336    // off0[4], off1[4]

// ---------------------------------------------------------------------------
// Kernel A (16 blocks x 256): routing + 4-parity MLP via wave reductions;
// weL/wcL/T recomputed per block (cheap); 45 clipped composed kernels and M
// partitioned across blocks.  (Verified in rounds 2/5.)
// ---------------------------------------------------------------------------
__global__ void prep_kernel(
    const float* __restrict__ WE,  const float* __restrict__ WC,
    const float* __restrict__ W2,
    const float* __restrict__ bw1, const float* __restrict__ bb1,
    const float* __restrict__ bw2, const float* __restrict__ bb2,
    const float* __restrict__ r2w, const float* __restrict__ r2b,
    const float* __restrict__ ow,  const float* __restrict__ ob,
    const float* __restrict__ l1w, const float* __restrict__ l1b,
    const float* __restrict__ l2w, const float* __restrict__ l2b,
    float* __restrict__ ws)
{
    __shared__ float weL[1440], wcL[1440], TL[2025];
    __shared__ float e1L[4][64];
    __shared__ float r2cL[16], rsumS[4], logitsL[2][4];
    const int tid  = threadIdx.x;
    const int bid  = blockIdx.x;
    const int lane = tid & 63, wid = tid >> 6;

    if (wid < 2) {
        float chv = wid ? 0.25f : -0.25f;
        int o = lane;
        float h = fmaxf(0.5f*l1w[2*o] + chv*l1w[2*o+1] + l1b[o], 0.f);
        float a0 = h*l2w[o], a1 = h*l2w[64+o], a2 = h*l2w[128+o], a3 = h*l2w[192+o];
        for (int off = 32; off; off >>= 1) {
            a0 += __shfl_down(a0, off); a1 += __shfl_down(a1, off);
            a2 += __shfl_down(a2, off); a3 += __shfl_down(a3, off);
        }
        if (lane == 0) {
            logitsL[wid][0] = a0 + l2b[0]; logitsL[wid][1] = a1 + l2b[1];
            logitsL[wid][2] = a2 + l2b[2]; logitsL[wid][3] = a3 + l2b[3];
        }
    }
    {
        float chv = (wid & 2) ? 0.25f : -0.25f;   // y parity
        float cwv = (wid & 1) ? 0.25f : -0.25f;   // x parity
        int o = lane;
        e1L[wid][o] = fmaxf(0.5f*bw1[3*o] + chv*bw1[3*o+1] + cwv*bw1[3*o+2] + bb1[o], 0.f);
    }
    __syncthreads();

    if (tid == 0) {
        float rs[4] = {0.f,0.f,0.f,0.f};
        for (int r = 0; r < 2; ++r) {
            float l0=logitsL[r][0], l1v=logitsL[r][1], l2v=logitsL[r][2], l3=logitsL[r][3];
            float mx = fmaxf(fmaxf(l0,l1v), fmaxf(l2v,l3));
            float e0=expf(l0-mx), e1=expf(l1v-mx), e2=expf(l2v-mx), e3=expf(l3-mx);
            float s = e0+e1+e2+e3;
            rs[0]+=e0/s; rs[1]+=e1/s; rs[2]+=e2/s; rs[3]+=e3/s;
        }
        rsumS[0]=rs[0]; rsumS[1]=rs[1]; rsumS[2]=rs[2]; rsumS[3]=rs[3];
    }
    {
        int o = lane;
        float acc = bb2[o];
        #pragma unroll 8
        for (int i = 0; i < 64; ++i) acc += e1L[wid][i]*bw2[o*64+i];
        float e2v = fmaxf(acc, 0.f);
        float v0 = e2v*ow[o],       v1 = e2v*ow[64+o];
        float r0 = e2v*r2w[o],      r1 = e2v*r2w[64+o];
        float r2v= e2v*r2w[128+o],  r3 = e2v*r2w[192+o];
        for (int off = 32; off; off >>= 1) {
            v0 += __shfl_down(v0, off);  v1 += __shfl_down(v1, off);
            r0 += __shfl_down(r0, off);  r1 += __shfl_down(r1, off);
            r2v+= __shfl_down(r2v, off); r3 += __shfl_down(r3, off);
        }
        if (lane == 0) {
            if (bid == 0) { ws[WS_OFF + wid] = v0 + ob[0]; ws[WS_OFF + 4 + wid] = v1 + ob[1]; }
            r2cL[wid*4+0] = 1.f/(1.f+expf(-(r0 + r2b[0])));
            r2cL[wid*4+1] = 1.f/(1.f+expf(-(r1 + r2b[1])));
            r2cL[wid*4+2] = 1.f/(1.f+expf(-(r2v+ r2b[2])));
            r2cL[wid*4+3] = 1.f/(1.f+expf(-(r3 + r2b[3])));
        }
    }
    __syncthreads();

    {
        float rs0=rsumS[0], rs1=rsumS[1], rs2=rsumS[2], rs3=rsumS[3];
        for (int idx = tid; idx < 1440; idx += 256) {
            weL[idx] = rs0*WE[idx] + rs1*WE[1440+idx] + rs2*WE[2880+idx] + rs3*WE[4320+idx];
            wcL[idx] = rs0*WC[idx] + rs1*WC[1440+idx] + rs2*WC[2880+idx] + rs3*WC[4320+idx];
        }
    }
    __syncthreads();

    for (int idx = tid; idx < 2025; idx += 256) {
        int s = idx / 45, t = idx % 45;
        float acc = 0.f;
        #pragma unroll 8
        for (int k = 0; k < 32; ++k) acc += wcL[k*45+s] * weL[k*45+t];
        TL[idx] = acc;
    }
    __syncthreads();

    {
        const int c0 = bid*633, c1 = (c0+633 < 10125) ? c0+633 : 10125;
        for (int idx = c0 + tid; idx < c1; idx += 256) {
            int cfg = idx / 225, u = idx % 225;
            int a = cfg/9, b = (cfg%9)/3, c = cfg%3;
            int ud = u/25, uy = (u%25)/5, ux = u%5;
            int sdlo = (a==0)?2:((a==1)?1:0);
            int sdhi = (a==4)?2:((a==3)?3:4);
            int sylo = (b==0)?1:0, syhi = (b==2)?1:2;
            int sxlo = (c==0)?1:0, sxhi = (c==2)?1:2;
            if (sdlo < ud-4) sdlo = ud-4;
            if (sdhi > ud)   sdhi = ud;
            if (sylo < uy-2) sylo = uy-2;
            if (syhi > uy)   syhi = uy;
            if (sxlo < ux-2) sxlo = ux-2;
            if (sxhi > ux)   sxhi = ux;
            float acc = 0.f;
            for (int sd = sdlo; sd <= sdhi; ++sd)
                for (int sy = sylo; sy <= syhi; ++sy)
                    for (int sx = sxlo; sx <= sxhi; ++sx)
                        acc += TL[(sd*9+sy*3+sx)*45 + (ud-sd)*9 + (uy-sy)*3 + (ux-sx)];
            ws[WS_WEFF + idx] = acc;
        }
    }

    {
        const int c0 = bid*241, c1 = (c0+241 < 3844) ? c0+241 : 3844;
        for (int idx = c0 + tid; idx < c1; idx += 256) {
            int cls = idx / 961, ij = idx % 961;
            float acc = 0.f;
            #pragma unroll
            for (int e = 0; e < 4; ++e) acc += r2cL[cls*4+e]*W2[e*961+ij];
            ws[WS_M + idx] = acc;
        }
    }
}

// ---------------------------------------------------------------------------
// Conv partial over taps [t0,t1): all 31 depths, weights from GLOBAL.
// INTER => statically-uniform cfg index => scalar s_load path.
// fs layout: fsA[d*156 + yy*13 + xx]  (8x8 tile, halo 2, stride 13)
// ---------------------------------------------------------------------------
template<bool INTER>
__device__ __forceinline__ void conv_part(const float* __restrict__ fsA,
                                          const float* __restrict__ wg,
                                          int bc, int ly, int lx,
                                          int t0, int t1, float o2[31])
{
    #pragma unroll 1
    for (int t = t0; t < t1; ++t) {
        const int uy = t / 5, ux = t - uy*5;
        float col[39];
        #pragma unroll
        for (int i = 0; i < 4; ++i) { col[i] = 0.f; col[35+i] = 0.f; }
        const float* f0 = fsA + (ly+uy)*13 + (lx+ux);
        #pragma unroll
        for (int i = 0; i < 31; ++i) col[4+i] = f0[i*156];

        float wA[5][9];
        #pragma unroll
        for (int a = 0; a < 5; ++a) {
            const int cfg = INTER ? (a*9 + 4) : (a*9 + bc);
            #pragma unroll
            for (int ud = 0; ud < 9; ++ud) wA[a][ud] = wg[cfg*225 + ud*25 + t];
        }
        #pragma unroll
        for (int ud = 0; ud < 9; ++ud) {
            o2[0]  += wA[0][ud] * col[ud];
            o2[1]  += wA[1][ud] * col[1+ud];
            o2[29] += wA[3][ud] * col[29+ud];
            o2[30] += wA[4][ud] * col[30+ud];
        }
        #pragma unroll
        for (int d = 2; d < 29; ++d) {
            #pragma unroll
            for (int ud = 0; ud < 9; ++ud)
                o2[d] += wA[2][ud] * col[d+ud];
        }
    }
}

// ---------------------------------------------------------------------------
// Kernel B: 1024 blocks (8x8 tile), 256 threads, 4 threads/pixel.
// Bilinear fill -> 4-way tap-split conv -> LDS combine tree (aliases fs) ->
// 4-way row-split 31x31 mix.  LDS ~34.7 KB -> 4 blocks/CU.
// ---------------------------------------------------------------------------
__global__ __launch_bounds__(256, 4)
void conv_kernel(const float* __restrict__ x, const float* __restrict__ ws,
                 float* __restrict__ out)
{
    __shared__ float fsA[4836];        // fs[31][12][13]; later aliased by bufs
    __shared__ float Ms[3844];
    float* buf0 = fsA;                 // [64][31] partials (after overlay sync)
    float* buf1 = fsA + 1984;
    const int tid = threadIdx.x;
    const int x0 = blockIdx.x * 8;
    const int y0 = blockIdx.y * 8;

    float off0[4], off1[4];
    #pragma unroll
    for (int c = 0; c < 4; ++c) { off0[c] = ws[WS_OFF+c]; off1[c] = ws[WS_OFF+4+c]; }

    for (int idx = tid; idx < 3844; idx += 256) Ms[idx] = ws[WS_M + idx];

    // ---- bilinear fill of the fea tile (31 x 12 x 12 used, stride 13) ----
    for (int idx = tid; idx < 4464; idx += 256) {
        int c  = idx / 144;
        int r  = idx % 144;
        int yy = r / 12, xx = r % 12;
        int gy = y0 + yy - 2, gx = x0 + xx - 2;
        float v = 0.f;
        if (gy >= 0 && gy < 256 && gx >= 0 && gx < 256) {
            int cls = ((gy & 1) << 1) | (gx & 1);
            float ix = (gx + 0.5f)*0.5f - 0.5f + off0[cls];
            float iy = (gy + 0.5f)*0.5f - 0.5f + off1[cls];
            float xf = floorf(ix), yf = floorf(iy);
            float wx = ix - xf, wy = iy - yf;
            int xi = (int)xf, yi = (int)yf;
            const float* xc = x + c*16384;
            float acc = 0.f;
            if (yi   >= 0 && yi   < 128 && xi   >= 0 && xi   < 128) acc += xc[yi*128+xi]       * (1.f-wy)*(1.f-wx);
            if (yi   >= 0 && yi   < 128 && xi+1 >= 0 && xi+1 < 128) acc += xc[yi*128+xi+1]     * (1.f-wy)*wx;
            if (yi+1 >= 0 && yi+1 < 128 && xi   >= 0 && xi   < 128) acc += xc[(yi+1)*128+xi]   * wy*(1.f-wx);
            if (yi+1 >= 0 && yi+1 < 128 && xi+1 >= 0 && xi+1 < 128) acc += xc[(yi+1)*128+xi+1] * wy*wx;
            v = acc;
        }
        fsA[c*156 + yy*13 + xx] = v;
    }
    __syncthreads();

    const int px = tid & 63, sub = tid >> 6;       // sub == wave id (uniform)
    const int lx = px & 7,  ly = px >> 3;
    const int gx = x0 + lx, gy = y0 + ly;
    const int bcls = (gy == 0) ? 0 : ((gy == 255) ? 2 : 1);
    const int ccls = (gx == 0) ? 0 : ((gx == 255) ? 2 : 1);
    const int bc = bcls*3 + ccls;
    const float* wg = ws + WS_WEFF;

    // tap split {0-6}{7-12}{13-18}{19-24}
    const int t0 = (sub == 0) ? 0 : 1 + sub*6;
    const int t1 = 7 + sub*6 > 25 ? 25 : 7 + sub*6;

    float o2[31];
    if (sub == 0) {
        #pragma unroll
        for (int d = 0; d < 31; ++d) o2[d] = fsA[d*156 + (ly+2)*13 + (lx+2)];  // conv2 residual (+fea)
    } else {
        #pragma unroll
        for (int d = 0; d < 31; ++d) o2[d] = 0.f;
    }

    const bool inter = (x0 != 0) & (x0 != 248) & (y0 != 0) & (y0 != 248);
    if (inter) conv_part<true >(fsA, wg, bc, ly, lx, t0, t1, o2);
    else       conv_part<false>(fsA, wg, bc, ly, lx, t0, t1, o2);

    // stash fea0 residual for my mix rows before bufs overlay fs
    const int i0 = sub * 8;
    const int nrow = (sub == 3) ? 7 : 8;
    float fsc[8];
    #pragma unroll
    for (int k = 0; k < 8; ++k)
        fsc[k] = (k < nrow) ? fsA[(i0+k)*156 + (ly+2)*13 + (lx+2)] : 0.f;
    __syncthreads();   // all fs reads complete; region becomes buf0/buf1

    // combine tree: (0+=1, 2+=3) then 0+=2
    if (sub == 1) {
        #pragma unroll
        for (int d = 0; d < 31; ++d) buf0[px*31+d] = o2[d];
    }
    if (sub == 3) {
        #pragma unroll
        for (int d = 0; d < 31; ++d) buf1[px*31+d] = o2[d];
    }
    __syncthreads();
    if (sub == 0) {
        #pragma unroll
        for (int d = 0; d < 31; ++d) o2[d] += buf0[px*31+d];
    }
    if (sub == 2) {
        #pragma unroll
        for (int d = 0; d < 31; ++d) { o2[d] += buf1[px*31+d]; buf1[px*31+d] = o2[d]; }
    }
    __syncthreads();
    if (sub == 0) {
        #pragma unroll
        for (int d = 0; d < 31; ++d) { o2[d] += buf1[px*31+d]; buf0[px*31+d] = o2[d]; }
    }
    __syncthreads();

    // ---- mix: out[i] = sum_j M[cls][i][j]*o2[j] + fea0[i], rows split 8/8/8/7
    const int cls = ((gy & 1) << 1) | (gx & 1);
    #pragma unroll 1
    for (int k = 0; k < 8; ++k) {
        if (k < nrow) {
            int i = i0 + k;
            float acc = fsc[k];
            #pragma unroll
            for (int j = 0; j < 31; ++j) acc += Ms[cls*961 + i*31 + j] * buf0[px*31+j];
            out[i*65536 + gy*256 + gx] = acc;
        }
    }
}

extern "C" void kernel_launch(void* const* d_in, const int* in_sizes, int n_in,
                              void* d_out, int out_size, void* d_ws, size_t ws_size,
                              hipStream_t stream)
{
    const float* x   = (const float*)d_in[0];
    // d_in[1] = scale (int, always 2; shapes are compile-time)
    const float* WE  = (const float*)d_in[2];
    const float* WC  = (const float*)d_in[3];
    const float* W2  = (const float*)d_in[4];
    const float* bw1 = (const float*)d_in[5];
    const float* bb1 = (const float*)d_in[6];
    const float* bw2 = (const float*)d_in[7];
    const float* bb2 = (const float*)d_in[8];
    const float* r2w = (const float*)d_in[9];
    const float* r2b = (const float*)d_in[10];
    const float* ow  = (const float*)d_in[11];
    const float* ob  = (const float*)d_in[12];
    const float* l1w = (const float*)d_in[13];
    const float* l1b = (const float*)d_in[14];
    const float* l2w = (const float*)d_in[15];
    const float* l2b = (const float*)d_in[16];
    float* ws  = (float*)d_ws;
    float* out = (float*)d_out;

    hipLaunchKernelGGL(prep_kernel, dim3(16), dim3(256), 0, stream,
                       WE, WC, W2, bw1, bb1, bw2, bb2, r2w, r2b,
                       ow, ob, l1w, l1b, l2w, l2b, ws);
    hipLaunchKernelGGL(conv_kernel, dim3(32, 32), dim3(256), 0, stream,
                       x, ws, out);
}